// Round 11
// baseline (5042.554 us; speedup 1.0000x reference)
//
#include <hip/hip_runtime.h>

#define BSZ 64
#define SLEN 32
#define HID 128
#define VOC 96
#define DEPTH 500
#define TPB 256             // 4 waves per block, one block per batch row
#define EPSV 1e-6f
#define CHK 12              // floats per 8-float h-chunk (8 data + 4 pad)

typedef __attribute__((ext_vector_type(2))) float f32x2;

#if defined(__has_builtin)
#if __has_builtin(__builtin_elementwise_fma)
#define VFMA(a, b, c) __builtin_elementwise_fma((a), (b), (c))
#endif
#endif
#ifndef VFMA
__device__ __forceinline__ f32x2 vfma_(f32x2 a, f32x2 b, f32x2 c) {
    f32x2 r; r.x = fmaf(a.x, b.x, c.x); r.y = fmaf(a.y, b.y, c.y); return r;
}
#define VFMA(a, b, c) vfma_((a), (b), (c))
#endif

__device__ __forceinline__ float rsq_fast(float x) {
    float r; asm("v_rsq_f32 %0, %1" : "=v"(r) : "v"(x)); return r;
}

// DPP helpers (ctrl is a compile-time template constant).
// 0xB1 = quad_perm xor1, 0x4E = quad_perm xor2,
// 0x141 = row_half_mirror (l -> 7-l within 8-lane half: crosses quads),
// 0x140 = row_mirror      (l -> 15-l within 16-lane row: crosses halves).
template <int CTRL>
__device__ __forceinline__ float qperm(float v) {
    return __int_as_float(__builtin_amdgcn_update_dpp(
        0, __float_as_int(v), CTRL, 0xF, 0xF, true));
}
// 16-lane reduction, pure VALU. After xor1+xor2 each quad is uniform, so
// row_half_mirror adds the other quad's sum; after that each 8-half is
// uniform, so row_mirror adds the other half's sum -> full 16-lane sum.
#define BFLY16(v)                                                              \
    v += qperm<0xB1>(v);                                                       \
    v += qperm<0x4E>(v);                                                       \
    v += qperm<0x141>(v);                                                      \
    v += qperm<0x140>(v);

__global__ __launch_bounds__(TPB, 1) void rnn_char_lm(
    const int* __restrict__ chars, const float* __restrict__ hidden,
    const float* __restrict__ embed_w, const float* __restrict__ W_g,
    const float* __restrict__ b_g, const float* __restrict__ pre_s,
    const float* __restrict__ post_s, const float* __restrict__ rw_g,
    const float* __restrict__ rb_g, float* __restrict__ out)
{
    __shared__ __align__(16) float hbuf[2][16 * CHK]; // chunked h, dbuf
    __shared__ float rwT[HID * VOC];                  // readout_w transposed [k][v]

    const int b = blockIdx.x;
    const int tid = threadIdx.x;
    const int w = tid >> 6;
    const int lane = tid & 63;
    const int g = lane >> 4;          // col-group: 8 consecutive cols (4/wave)
    const int ch = lane & 15;         // k-chunk: 8 k-values (16 chunks)

    const int col0 = 32 * w + 8 * g;  // lane's 8 cols: col0..col0+7
    const int cblk = 4 * w + g;       // chunk index of lane's col block
    const int rbase = CHK * ch;       // read chunk base (float idx)
    // write slot: lanes ch<2 write half each (one exec-masked b128 per wave)
    const int wslot = CHK * cblk + 4 * (ch & 1);

    // one-time: stage readout_w transposed into LDS (round-2 proven)
    for (int e = tid; e < VOC * HID; e += TPB) {
        int v = e >> 7;
        int k = e & (HID - 1);
        rwT[k * VOC + v] = rw_g[e];
    }

    // one-time: W' = pre_scale[k]*W[k][col0+c], packed over k-pairs. 64 VGPRs.
    f32x2 W2[8][4];
#pragma unroll
    for (int q = 0; q < 4; ++q) {
        int k0 = 8 * ch + 2 * q;
        float p0 = pre_s[k0], p1 = pre_s[k0 + 1];
#pragma unroll
        for (int c = 0; c < 8; ++c) {
            f32x2 t;
            t.x = p0 * W_g[k0 * HID + col0 + c];
            t.y = p1 * W_g[(k0 + 1) * HID + col0 + c];
            W2[c][q] = t;
        }
    }
    float bvv[8], psvv[8];
    {
        float4 b0 = *(const float4*)&b_g[col0];
        float4 b1 = *(const float4*)&b_g[col0 + 4];
        float4 p0 = *(const float4*)&post_s[col0];
        float4 p1 = *(const float4*)&post_s[col0 + 4];
        bvv[0]=b0.x; bvv[1]=b0.y; bvv[2]=b0.z; bvv[3]=b0.w;
        bvv[4]=b1.x; bvv[5]=b1.y; bvv[6]=b1.z; bvv[7]=b1.w;
        psvv[0]=p0.x; psvv[1]=p0.y; psvv[2]=p0.z; psvv[3]=p0.w;
        psvv[4]=p1.x; psvv[5]=p1.y; psvv[6]=p1.z; psvv[7]=p1.w;
    }
    const float rbv = (tid < VOC) ? rb_g[tid] : 0.0f;

    // h for lane's 8 cols (replicated across the 16 ch-lanes of group g)
    float hc[8];
    {
        float4 h0 = *(const float4*)&hidden[b * HID + col0];
        float4 h1 = *(const float4*)&hidden[b * HID + col0 + 4];
        hc[0]=h0.x; hc[1]=h0.y; hc[2]=h0.z; hc[3]=h0.w;
        hc[4]=h1.x; hc[5]=h1.y; hc[6]=h1.z; hc[7]=h1.w;
    }
    if (ch == 0) {
        *(float4*)&hbuf[0][CHK * cblk]     = make_float4(hc[0],hc[1],hc[2],hc[3]);
        *(float4*)&hbuf[0][CHK * cblk + 4] = make_float4(hc[4],hc[5],hc[6],hc[7]);
    }
    __syncthreads();

// one recurrent iteration at compile-time read-parity P (reads P, writes P^1)
#define ITER(P)                                                                \
    {                                                                          \
        const float4* rb = (const float4*)&hbuf[P][rbase];                     \
        float4 x0 = rb[0], x1 = rb[1];                                         \
        f32x2 a0={0,0},a1={0,0},a2={0,0},a3={0,0};                             \
        f32x2 a4={0,0},a5={0,0},a6={0,0},a7={0,0},s={0,0};                     \
        _Pragma("unroll")                                                      \
        for (int q = 0; q < 4; ++q) {                                          \
            f32x2 hv;                                                          \
            hv.x = (q == 0) ? x0.x : (q == 1) ? x0.z : (q == 2) ? x1.x : x1.z; \
            hv.y = (q == 0) ? x0.y : (q == 1) ? x0.w : (q == 2) ? x1.y : x1.w; \
            s  = VFMA(hv, hv, s);                                              \
            a0 = VFMA(hv, W2[0][q], a0);                                       \
            a1 = VFMA(hv, W2[1][q], a1);                                       \
            a2 = VFMA(hv, W2[2][q], a2);                                       \
            a3 = VFMA(hv, W2[3][q], a3);                                       \
            a4 = VFMA(hv, W2[4][q], a4);                                       \
            a5 = VFMA(hv, W2[5][q], a5);                                       \
            a6 = VFMA(hv, W2[6][q], a6);                                       \
            a7 = VFMA(hv, W2[7][q], a7);                                       \
        }                                                                      \
        float y0=a0.x+a0.y, y1=a1.x+a1.y, y2=a2.x+a2.y, y3=a3.x+a3.y;          \
        float y4=a4.x+a4.y, y5=a5.x+a5.y, y6=a6.x+a6.y, y7=a7.x+a7.y;          \
        float ssl = s.x + s.y;                                                 \
        BFLY16(y0) BFLY16(y1) BFLY16(y2) BFLY16(y3)                            \
        BFLY16(y4) BFLY16(y5) BFLY16(y6) BFLY16(y7) BFLY16(ssl)                \
        const float rn = rsq_fast(fmaf(ssl, 1.0f / HID, EPSV));                \
        hc[0] += fmaxf(fmaf(y0, rn, evv[0]), 0.0f);                            \
        hc[1] += fmaxf(fmaf(y1, rn, evv[1]), 0.0f);                            \
        hc[2] += fmaxf(fmaf(y2, rn, evv[2]), 0.0f);                            \
        hc[3] += fmaxf(fmaf(y3, rn, evv[3]), 0.0f);                            \
        hc[4] += fmaxf(fmaf(y4, rn, evv[4]), 0.0f);                            \
        hc[5] += fmaxf(fmaf(y5, rn, evv[5]), 0.0f);                            \
        hc[6] += fmaxf(fmaf(y6, rn, evv[6]), 0.0f);                            \
        hc[7] += fmaxf(fmaf(y7, rn, evv[7]), 0.0f);                            \
        if (ch < 2) {                                                          \
            float4 wd;                                                         \
            wd.x = ch ? hc[4] : hc[0];                                         \
            wd.y = ch ? hc[5] : hc[1];                                         \
            wd.z = ch ? hc[6] : hc[2];                                         \
            wd.w = ch ? hc[7] : hc[3];                                         \
            *(float4*)&hbuf[P ^ 1][wslot] = wd;                                \
        }                                                                      \
        __syncthreads();                                                       \
    }

    for (int t = 0; t < SLEN; ++t) {
        const int c = chars[b * SLEN + t];
        float evv[8];
        {
            float4 e0 = *(const float4*)&embed_w[c * HID + col0];
            float4 e1 = *(const float4*)&embed_w[c * HID + col0 + 4];
            evv[0]=e0.x+bvv[0]; evv[1]=e0.y+bvv[1];
            evv[2]=e0.z+bvv[2]; evv[3]=e0.w+bvv[3];
            evv[4]=e1.x+bvv[4]; evv[5]=e1.y+bvv[5];
            evv[6]=e1.z+bvv[6]; evv[7]=e1.w+bvv[7];
        }

        for (int it = 0; it < DEPTH / 2; ++it) {
            ITER(0)
            ITER(1)
        }
        // after 500 iters, current h sits in hbuf[0]; parity invariant per t.

        // ---- epilogue: post-norm (replaces h) + readout ----
        {
            const float4* rb = (const float4*)&hbuf[0][rbase];
            float4 x0 = rb[0], x1 = rb[1];
            f32x2 s = {0, 0};
            f32x2 hv;
            hv.x = x0.x; hv.y = x0.y; s = VFMA(hv, hv, s);
            hv.x = x0.z; hv.y = x0.w; s = VFMA(hv, hv, s);
            hv.x = x1.x; hv.y = x1.y; s = VFMA(hv, hv, s);
            hv.x = x1.z; hv.y = x1.w; s = VFMA(hv, hv, s);
            float ssl = s.x + s.y;
            BFLY16(ssl)
            const float rnp = 1.0f / sqrtf(ssl * (1.0f / HID) + EPSV);
#pragma unroll
            for (int cc = 0; cc < 8; ++cc) hc[cc] *= rnp * psvv[cc];
            __syncthreads();                         // all ss-reads of hbuf[0] done
            if (ch == 0) {                           // hpost, chunked layout
                *(float4*)&hbuf[0][CHK * cblk]     = make_float4(hc[0],hc[1],hc[2],hc[3]);
                *(float4*)&hbuf[0][CHK * cblk + 4] = make_float4(hc[4],hc[5],hc[6],hc[7]);
            }
            __syncthreads();                         // visible to readout + next t
        }

        if (tid < VOC) {
            float acc0 = 0.0f, acc1 = 0.0f;
#pragma unroll
            for (int C = 0; C < 16; ++C) {
                const float4 x0 = *(const float4*)&hbuf[0][CHK * C];
                const float4 x1 = *(const float4*)&hbuf[0][CHK * C + 4];
                const int k = 8 * C;
                acc0 = fmaf(x0.x, rwT[(k + 0) * VOC + tid], acc0);
                acc1 = fmaf(x0.y, rwT[(k + 1) * VOC + tid], acc1);
                acc0 = fmaf(x0.z, rwT[(k + 2) * VOC + tid], acc0);
                acc1 = fmaf(x0.w, rwT[(k + 3) * VOC + tid], acc1);
                acc0 = fmaf(x1.x, rwT[(k + 4) * VOC + tid], acc0);
                acc1 = fmaf(x1.y, rwT[(k + 5) * VOC + tid], acc1);
                acc0 = fmaf(x1.z, rwT[(k + 6) * VOC + tid], acc0);
                acc1 = fmaf(x1.w, rwT[(k + 7) * VOC + tid], acc1);
            }
            out[(b * SLEN + t) * VOC + tid] = acc0 + acc1 + rbv;
        }
        // non-readout waves run ahead into next t's ITER(0): they only READ
        // hbuf[0]; the first write targets hbuf[1] and is barrier-gated.
    }

    if (ch == 0) {
        *(float4*)&out[BSZ * SLEN * VOC + b * HID + col0] =
            make_float4(hc[0], hc[1], hc[2], hc[3]);
        *(float4*)&out[BSZ * SLEN * VOC + b * HID + col0 + 4] =
            make_float4(hc[4], hc[5], hc[6], hc[7]);
    }

#undef ITER
}

extern "C" void kernel_launch(void* const* d_in, const int* in_sizes, int n_in,
                              void* d_out, int out_size, void* d_ws, size_t ws_size,
                              hipStream_t stream)
{
    const int* chars      = (const int*)d_in[0];
    const float* hidden   = (const float*)d_in[1];
    const float* embed_w  = (const float*)d_in[2];
    const float* W_g      = (const float*)d_in[3];
    const float* b_g      = (const float*)d_in[4];
    const float* pre_s    = (const float*)d_in[5];
    const float* post_s   = (const float*)d_in[6];
    const float* rw_g     = (const float*)d_in[7];
    const float* rb_g     = (const float*)d_in[8];
    float* out            = (float*)d_out;

    rnn_char_lm<<<dim3(BSZ), dim3(TPB), 0, stream>>>(
        chars, hidden, embed_w, W_g, b_g, pre_s, post_s, rw_g, rb_g, out);
}